// Round 4
// baseline (1369.772 us; speedup 1.0000x reference)
//
#include <hip/hip_runtime.h>
#include <stdint.h>

typedef unsigned short u16;
typedef unsigned int u32;
typedef __attribute__((ext_vector_type(4))) float f32x4;
typedef __attribute__((ext_vector_type(8))) short bf16x8;

#define NN 32768
#define EE 524288
#define DD 384
#define NREL 8
#define NGR 128
#define KREL (NREL * DD)  // 3072
#define LN2 (2 * DD)      // 768

__device__ __forceinline__ float bf2f(u16 u) {
  union { u32 u; float f; } v; v.u = ((u32)u) << 16; return v.f;
}
__device__ __forceinline__ u16 f2bf(float f) {
  union { float f; u32 u; } v; v.f = f;
  u32 r = v.u + 0x7fffu + ((v.u >> 16) & 1u);
  return (u16)(r >> 16);
}
__device__ __forceinline__ float2 up2(u32 p) {
  return make_float2(bf2f((u16)(p & 0xffffu)), bf2f((u16)(p >> 16)));
}
__device__ __forceinline__ u32 pk2(float a, float b) {
  return (u32)f2bf(a) | ((u32)f2bf(b) << 16);
}
// async 16B global->LDS (LDS dest = wave-uniform base + lane*16)
__device__ __forceinline__ void gl16(const u16* g, char* s) {
  __builtin_amdgcn_global_load_lds(
      (const __attribute__((address_space(1))) unsigned int*)(const void*)g,
      (__attribute__((address_space(3))) unsigned int*)(void*)s, 16, 0, 0);
}

// ---- per-node: nrm = |x|, Hn = bf16(x/|x|) ; zero cur ----
__global__ __launch_bounds__(256) void k_invnorm(const float* __restrict__ x,
                                                 float* __restrict__ nrm,
                                                 u16* __restrict__ hn,
                                                 int* __restrict__ cur) {
  const int gid = blockIdx.x * 256 + threadIdx.x;
  if (gid < NN) cur[gid] = 0;
  const int node = gid >> 6;
  const int l = threadIdx.x & 63;
  const float* row = x + (size_t)node * DD;
  float v[6];
  float s = 0.f;
#pragma unroll
  for (int j = 0; j < 6; ++j) { v[j] = row[l + 64 * j]; s += v[j] * v[j]; }
#pragma unroll
  for (int off = 32; off > 0; off >>= 1) s += __shfl_xor(s, off, 64);
  const float inv = rsqrtf(s);
  if (l == 0) nrm[node] = s * inv;  // sqrt(s)
  u16* hr = hn + (size_t)node * DD;
#pragma unroll
  for (int j = 0; j < 6; ++j) hr[l + 64 * j] = f2bf(v[j] * inv);
}

// ---- weight transpose + bf16 convert ----
__global__ void k_prepW(const float* __restrict__ Wrel, const float* __restrict__ Wmp,
                        const float* __restrict__ Wself,
                        u16* __restrict__ WcatT, u16* __restrict__ WmsT) {
  const int i = blockIdx.x * 256 + threadIdx.x;
  const int total1 = DD * KREL;
  const int total2 = LN2 * DD;
  if (i < total1) {
    const int n = i / KREL, k = i % KREL;
    WcatT[i] = f2bf(Wrel[(size_t)k * DD + n]);
  } else if (i < total1 + total2) {
    const int ii = i - total1;
    const int j = ii / DD, k = ii % DD;
    const float v = (j < DD) ? Wmp[k * DD + j] : Wself[k * DD + (j - DD)];
    WmsT[ii] = f2bf(v);
  }
}

__global__ void k_hist(const int* __restrict__ ei, int* __restrict__ cnt) {
  const int e = blockIdx.x * 256 + threadIdx.x;
  atomicAdd(&cnt[ei[EE + e]], 1);
}

// single block, 1024 threads: exclusive scan of 32768 degrees
__global__ __launch_bounds__(1024) void k_scan(const int* __restrict__ deg,
                                               int* __restrict__ rp,
                                               int* __restrict__ cur) {
  __shared__ int ps[1024];
  const int t = threadIdx.x;
  const int base = t * 32;
  int loc[32];
  int tot = 0;
#pragma unroll
  for (int j = 0; j < 32; ++j) { loc[j] = tot; tot += deg[base + j]; }
  ps[t] = tot;
  __syncthreads();
  for (int off = 1; off < 1024; off <<= 1) {
    const int v = (t >= off) ? ps[t - off] : 0;
    __syncthreads();
    ps[t] += v;
    __syncthreads();
  }
  const int myoff = ps[t] - tot;  // exclusive
#pragma unroll
  for (int j = 0; j < 32; ++j) {
    const int val = myoff + loc[j];
    rp[base + j] = val;
    cur[base + j] = val;
  }
  if (t == 1023) rp[NN] = EE;
}

__global__ void k_scatter(const int* __restrict__ ei, const int* __restrict__ etype,
                          int* __restrict__ cur, int* __restrict__ epack) {
  const int e = blockIdx.x * 256 + threadIdx.x;
  const int d = ei[EE + e];
  const int pos = atomicAdd(&cur[d], 1);
  epack[pos] = ei[e] | (etype[e] << 16);
}

// ---- LAYER 0 fused: wave per node; compute cos weight + aggregate in one pass ----
// Hn = normalized bf16 rows; accumulates w*nrm[src]*Hn[src] (= w*x[src]);
// writes wsort[e] (reused by layer 1), agg, sbuf.
#define ACC6(A0, A1, A2, S) \
  A0.x += wn * v0.x; A0.y += wn * v0.y; \
  A1.x += wn * v1.x; A1.y += wn * v1.y; \
  A2.x += wn * v2.x; A2.y += wn * v2.y; S += w;

__global__ __launch_bounds__(256) void k_edge_rel_f(
    const u16* __restrict__ Hn, const float* __restrict__ nrm,
    const int* __restrict__ rp, const int* __restrict__ epack,
    const float* __restrict__ ncs, float* __restrict__ wsort,
    u16* __restrict__ agg, float* __restrict__ sbuf, int base) {
  const int loc = (blockIdx.x << 2) + (threadIdx.x >> 6);
  const int node = base + loc;
  const int l = threadIdx.x & 63;
  const u32* rq = (const u32*)(Hn + (size_t)node * DD);
  const float2 q0 = up2(rq[l]), q1 = up2(rq[l + 64]), q2 = up2(rq[l + 128]);
  const float ncsl = ncs[l & 7];
  const int e0 = rp[node], e1 = rp[node + 1];
  float2 a00 = {0,0}, a01 = {0,0}, a02 = {0,0};
  float2 a10 = {0,0}, a11 = {0,0}, a12 = {0,0};
  float2 a20 = {0,0}, a21 = {0,0}, a22 = {0,0};
  float2 a30 = {0,0}, a31 = {0,0}, a32 = {0,0};
  float2 a40 = {0,0}, a41 = {0,0}, a42 = {0,0};
  float2 a50 = {0,0}, a51 = {0,0}, a52 = {0,0};
  float2 a60 = {0,0}, a61 = {0,0}, a62 = {0,0};
  float2 a70 = {0,0}, a71 = {0,0}, a72 = {0,0};
  float s0 = 0, s1 = 0, s2 = 0, s3 = 0, s4 = 0, s5 = 0, s6 = 0, s7 = 0;
  for (int e = e0; e < e1; ++e) {
    const int pk = epack[e];
    const int src = pk & 0xffff;
    const int ty = pk >> 16;
    const float nr = nrm[src];
    const u32* rs = (const u32*)(Hn + (size_t)src * DD);
    const float2 v0 = up2(rs[l]), v1 = up2(rs[l + 64]), v2 = up2(rs[l + 128]);
    float d = q0.x * v0.x + q0.y * v0.y + q1.x * v1.x + q1.y * v1.y +
              q2.x * v2.x + q2.y * v2.y;
#pragma unroll
    for (int off = 32; off > 0; off >>= 1) d += __shfl_xor(d, off, 64);
    const float w = d / __shfl(ncsl, ty, 64);
    if (l == 0) wsort[e] = w;
    const float wn = w * nr;
    switch (ty) {
      case 0: ACC6(a00, a01, a02, s0) break;
      case 1: ACC6(a10, a11, a12, s1) break;
      case 2: ACC6(a20, a21, a22, s2) break;
      case 3: ACC6(a30, a31, a32, s3) break;
      case 4: ACC6(a40, a41, a42, s4) break;
      case 5: ACC6(a50, a51, a52, s5) break;
      case 6: ACC6(a60, a61, a62, s6) break;
      default: ACC6(a70, a71, a72, s7) break;
    }
  }
  u32* ap = (u32*)(agg + (size_t)loc * KREL);
  ap[0 * 192 + l] = pk2(a00.x, a00.y); ap[0 * 192 + 64 + l] = pk2(a01.x, a01.y); ap[0 * 192 + 128 + l] = pk2(a02.x, a02.y);
  ap[1 * 192 + l] = pk2(a10.x, a10.y); ap[1 * 192 + 64 + l] = pk2(a11.x, a11.y); ap[1 * 192 + 128 + l] = pk2(a12.x, a12.y);
  ap[2 * 192 + l] = pk2(a20.x, a20.y); ap[2 * 192 + 64 + l] = pk2(a21.x, a21.y); ap[2 * 192 + 128 + l] = pk2(a22.x, a22.y);
  ap[3 * 192 + l] = pk2(a30.x, a30.y); ap[3 * 192 + 64 + l] = pk2(a31.x, a31.y); ap[3 * 192 + 128 + l] = pk2(a32.x, a32.y);
  ap[4 * 192 + l] = pk2(a40.x, a40.y); ap[4 * 192 + 64 + l] = pk2(a41.x, a41.y); ap[4 * 192 + 128 + l] = pk2(a42.x, a42.y);
  ap[5 * 192 + l] = pk2(a50.x, a50.y); ap[5 * 192 + 64 + l] = pk2(a51.x, a51.y); ap[5 * 192 + 128 + l] = pk2(a52.x, a52.y);
  ap[6 * 192 + l] = pk2(a60.x, a60.y); ap[6 * 192 + 64 + l] = pk2(a61.x, a61.y); ap[6 * 192 + 128 + l] = pk2(a62.x, a62.y);
  ap[7 * 192 + l] = pk2(a70.x, a70.y); ap[7 * 192 + 64 + l] = pk2(a71.x, a71.y); ap[7 * 192 + 128 + l] = pk2(a72.x, a72.y);
  if (l == 0) {
    float* sp = sbuf + (size_t)node * 8;
    sp[0] = s0; sp[1] = s1; sp[2] = s2; sp[3] = s3;
    sp[4] = s4; sp[5] = s5; sp[6] = s6; sp[7] = s7;
  }
}

// ---- LAYER 1 aggregation (precomputed wsort) ----
__global__ __launch_bounds__(192) void k_edge_rel(
    const u16* __restrict__ H, const int* __restrict__ rp,
    const int* __restrict__ epack, const float* __restrict__ wsort,
    u16* __restrict__ agg, float* __restrict__ sbuf, int base) {
  const int i = base + blockIdx.x;
  const int t = threadIdx.x;
  const int e0 = rp[i], e1 = rp[i + 1];
  float2 a0 = {0, 0}, a1 = {0, 0}, a2 = {0, 0}, a3 = {0, 0};
  float2 a4 = {0, 0}, a5 = {0, 0}, a6 = {0, 0}, a7 = {0, 0};
  float s0 = 0, s1 = 0, s2 = 0, s3 = 0, s4 = 0, s5 = 0, s6 = 0, s7 = 0;
  for (int e = e0; e < e1; ++e) {
    const int pk = epack[e];
    const float w = wsort[e];
    const int src = pk & 0xffff;
    const int ty = pk >> 16;
    const float2 hv = up2(*(const u32*)(H + (size_t)src * DD + 2 * t));
    const float vx = w * hv.x, vy = w * hv.y;
    switch (ty) {
      case 0: a0.x += vx; a0.y += vy; if (t == 0) s0 += w; break;
      case 1: a1.x += vx; a1.y += vy; if (t == 0) s1 += w; break;
      case 2: a2.x += vx; a2.y += vy; if (t == 0) s2 += w; break;
      case 3: a3.x += vx; a3.y += vy; if (t == 0) s3 += w; break;
      case 4: a4.x += vx; a4.y += vy; if (t == 0) s4 += w; break;
      case 5: a5.x += vx; a5.y += vy; if (t == 0) s5 += w; break;
      case 6: a6.x += vx; a6.y += vy; if (t == 0) s6 += w; break;
      default: a7.x += vx; a7.y += vy; if (t == 0) s7 += w; break;
    }
  }
  u32* ap = (u32*)(agg + (size_t)blockIdx.x * KREL);
  ap[0 * 192 + t] = pk2(a0.x, a0.y);
  ap[1 * 192 + t] = pk2(a1.x, a1.y);
  ap[2 * 192 + t] = pk2(a2.x, a2.y);
  ap[3 * 192 + t] = pk2(a3.x, a3.y);
  ap[4 * 192 + t] = pk2(a4.x, a4.y);
  ap[5 * 192 + t] = pk2(a5.x, a5.y);
  ap[6 * 192 + t] = pk2(a6.x, a6.y);
  ap[7 * 192 + t] = pk2(a7.x, a7.y);
  if (t == 0) {
    float* sp = sbuf + (size_t)i * 8;
    sp[0] = s0; sp[1] = s1; sp[2] = s2; sp[3] = s3;
    sp[4] = s4; sp[5] = s5; sp[6] = s6; sp[7] = s7;
  }
}

// ---- bf16 MFMA GEMM, output tile 128 x 384 per block, 512 thr / 8 waves ----
// C = A[M,K] @ Bt[nb:nb+384, K]^T ; BK=64, global_load_lds staging.
// mode 0: o = bf16(relu(C + s @ b_rel))            (rel GEMM, nb=0)
// mode 1: o = bf16(C + (col<384 ? b_mp : b_self))  (mp GEMM, nb=blockIdx.x*384)
__global__ __launch_bounds__(512, 2) void k_gemm(
    const u16* __restrict__ A, const u16* __restrict__ Bt, int K, int mode,
    u16* __restrict__ o_bf, int ostride,
    const float* __restrict__ sbuf, const float* __restrict__ brel,
    const float* __restrict__ bmp, const float* __restrict__ bself) {
  __shared__ __align__(16) u16 As[128 * 64];   // 16 KB
  __shared__ __align__(16) u16 Bs[384 * 64];   // 48 KB
  const int tid = threadIdx.x;
  const int nb = blockIdx.x * 384;
  const int mb = blockIdx.y * 128;
  const int w = tid >> 6, l = tid & 63;
  const int wr = (w >> 2) * 64;   // 0,64
  const int wc = (w & 3) * 96;    // 0,96,192,288
  const int srow = w * 8 + (l >> 3);   // 0..63 staging row
  const int scol = (l & 7) * 8;        // staging u16 col
  const int lr = l & 15;
  const int lk = (l >> 4) * 8;
  char* asb = (char*)As + w * 1024;
  char* bsb = (char*)Bs + w * 1024;
  f32x4 acc[4][6] = {};
  const u16* ag = A + (size_t)(mb + srow) * K + scol;
  const u16* bg = Bt + (size_t)(nb + srow) * K + scol;
  const size_t r64 = (size_t)64 * K;
  for (int k0 = 0; k0 < K; k0 += 64) {
    gl16(ag + k0,       asb);
    gl16(ag + k0 + r64, asb + 8192);
#pragma unroll
    for (int j = 0; j < 6; ++j)
      gl16(bg + k0 + j * r64, bsb + j * 8192);
    __syncthreads();
#pragma unroll
    for (int kk = 0; kk < 64; kk += 32) {
      bf16x8 af[4], bfr[6];
#pragma unroll
      for (int m = 0; m < 4; ++m)
        af[m] = *(const bf16x8*)(As + (wr + m * 16 + lr) * 64 + kk + lk);
#pragma unroll
      for (int n = 0; n < 6; ++n)
        bfr[n] = *(const bf16x8*)(Bs + (wc + n * 16 + lr) * 64 + kk + lk);
#pragma unroll
      for (int m = 0; m < 4; ++m)
#pragma unroll
        for (int n = 0; n < 6; ++n)
          acc[m][n] = __builtin_amdgcn_mfma_f32_16x16x32_bf16(af[m], bfr[n], acc[m][n], 0, 0, 0);
    }
    __syncthreads();
  }
  const int lg = l >> 4;
#pragma unroll
  for (int n = 0; n < 6; ++n) {
    const int col = nb + wc + n * 16 + lr;
    float bcol[8];
    if (mode == 0) {
#pragma unroll
      for (int r = 0; r < 8; ++r) bcol[r] = brel[r * DD + col];
    }
    float bb = 0.f;
    if (mode == 1) bb = (col < DD) ? bmp[col] : bself[col - DD];
#pragma unroll
    for (int m = 0; m < 4; ++m) {
#pragma unroll
      for (int q = 0; q < 4; ++q) {
        const int row = mb + wr + m * 16 + lg * 4 + q;
        float v = acc[m][n][q];
        if (mode == 0) {
          const float* sp = sbuf + (size_t)row * 8;
          float bias = 0.f;
#pragma unroll
          for (int r = 0; r < 8; ++r) bias += sp[r] * bcol[r];
          v = fmaxf(v + bias, 0.f);
        } else {
          v += bb;
        }
        o_bf[(size_t)row * ostride + col] = f2bf(v);
      }
    }
  }
}

// ---- MP aggregation + self + relu ----
__global__ __launch_bounds__(192) void k_edge_mp(
    const u16* __restrict__ lin2, const int* __restrict__ rp,
    const int* __restrict__ epack, u16* __restrict__ Hout) {
  const int i = blockIdx.x, t = threadIdx.x;
  const int e0 = rp[i], e1 = rp[i + 1];
  float ax = 0.f, ay = 0.f;
  for (int e = e0; e < e1; ++e) {
    const int src = epack[e] & 0xffff;
    const float2 hv = up2(*(const u32*)(lin2 + (size_t)src * LN2 + 2 * t));
    ax += hv.x; ay += hv.y;
  }
  const float2 sl = up2(*(const u32*)(lin2 + (size_t)i * LN2 + DD + 2 * t));
  ax = fmaxf(ax + sl.x, 0.f);
  ay = fmaxf(ay + sl.y, 0.f);
  *(u32*)(Hout + (size_t)i * DD + 2 * t) = pk2(ax, ay);
}

// ---- mean over 256 nodes per graph ----
__global__ __launch_bounds__(192) void k_mean(const u16* __restrict__ H,
                                              float* __restrict__ out) {
  const int g = blockIdx.x, t = threadIdx.x;
  float ax = 0.f, ay = 0.f;
  const u16* base = H + (size_t)g * 256 * DD;
  for (int j = 0; j < 256; ++j) {
    const float2 hv = up2(*(const u32*)(base + (size_t)j * DD + 2 * t));
    ax += hv.x; ay += hv.y;
  }
  out[g * DD + 2 * t]     = ax * (1.f / 256.f);
  out[g * DD + 2 * t + 1] = ay * (1.f / 256.f);
}

extern "C" void kernel_launch(void* const* d_in, const int* in_sizes, int n_in,
                              void* d_out, int out_size, void* d_ws, size_t ws_size,
                              hipStream_t stream) {
  const float* x     = (const float*)d_in[0];
  const int*   ei    = (const int*)d_in[1];
  const int*   ety   = (const int*)d_in[2];
  const float* Wrel  = (const float*)d_in[4];
  const float* brel  = (const float*)d_in[5];
  const float* ncs   = (const float*)d_in[6];
  const float* Wmp   = (const float*)d_in[7];
  const float* bmp   = (const float*)d_in[8];
  const float* Wself = (const float*)d_in[9];
  const float* bself = (const float*)d_in[10];
  float* out = (float*)d_out;
  (void)in_sizes; (void)n_in; (void)out_size;

  char* ws = (char*)d_ws;
  size_t off = 0;
  auto alloc = [&](size_t bytes) {
    void* p = ws + off;
    off = (off + bytes + 255) & ~(size_t)255;
    return p;
  };
  float* nrm   = (float*)alloc((size_t)NN * 4);
  int*   rp    = (int*)alloc(((size_t)NN + 1) * 4);
  int*   cur   = (int*)alloc((size_t)NN * 4);
  float* sbuf  = (float*)alloc((size_t)NN * 8 * 4);
  int*   epack = (int*)alloc((size_t)EE * 4);
  float* wsort = (float*)alloc((size_t)EE * 4);
  u16*   WcatT = (u16*)alloc((size_t)DD * KREL * 2);
  u16*   WmsT  = (u16*)alloc((size_t)LN2 * DD * 2);
  u16*   Hn    = (u16*)alloc((size_t)NN * DD * 2);
  u16*   H     = (u16*)alloc((size_t)NN * DD * 2);
  u16*   H2    = (u16*)alloc((size_t)NN * DD * 2);
  u16*   lin2  = (u16*)alloc((size_t)NN * LN2 * 2);
  size_t remain = (ws_size > off) ? (ws_size - off) : 0;
  int C = NN;
  while (C > 1024 && (size_t)C * KREL * 2 > remain) C >>= 1;
  u16* agg = (u16*)(ws + off);

  k_invnorm<<<NN / 4, 256, 0, stream>>>(x, nrm, Hn, cur);
  k_prepW<<<(DD * KREL + LN2 * DD) / 256, 256, 0, stream>>>(Wrel, Wmp, Wself, WcatT, WmsT);
  k_hist<<<EE / 256, 256, 0, stream>>>(ei, cur);
  k_scan<<<1, 1024, 0, stream>>>(cur, rp, cur);
  k_scatter<<<EE / 256, 256, 0, stream>>>(ei, ety, cur, epack);

  // ---- layer 0 (fused cos) ----
  for (int c0 = 0; c0 < NN; c0 += C) {
    k_edge_rel_f<<<C / 4, 256, 0, stream>>>(Hn, nrm, rp, epack, ncs, wsort, agg, sbuf, c0);
    k_gemm<<<dim3(1, C / 128), 512, 0, stream>>>(agg, WcatT, KREL, 0,
                                                 H2 + (size_t)c0 * DD, DD,
                                                 sbuf + (size_t)c0 * 8, brel, nullptr, nullptr);
  }
  k_gemm<<<dim3(2, NN / 128), 512, 0, stream>>>(H2, WmsT, DD, 1,
                                                lin2, LN2, nullptr, nullptr, bmp, bself);
  k_edge_mp<<<NN, 192, 0, stream>>>(lin2, rp, epack, H);

  // ---- layer 1 ----
  for (int c0 = 0; c0 < NN; c0 += C) {
    k_edge_rel<<<C, 192, 0, stream>>>(H, rp, epack, wsort, agg, sbuf, c0);
    k_gemm<<<dim3(1, C / 128), 512, 0, stream>>>(agg, WcatT, KREL, 0,
                                                 H2 + (size_t)c0 * DD, DD,
                                                 sbuf + (size_t)c0 * 8, brel, nullptr, nullptr);
  }
  k_gemm<<<dim3(2, NN / 128), 512, 0, stream>>>(H2, WmsT, DD, 1,
                                                lin2, LN2, nullptr, nullptr, bmp, bself);
  k_edge_mp<<<NN, 192, 0, stream>>>(lin2, rp, epack, H);

  k_mean<<<NGR, 192, 0, stream>>>(H, out);
}